// Round 7
// baseline (272.662 us; speedup 1.0000x reference)
//
#include <hip/hip_runtime.h>
#include <cstdint>

#define NN 16
#define W64 64
#define MT 64                    // M elements per workgroup
#define NSTAGE 17                // stage 0 = W1/f, stages 1..16 = graph nodes
#define IST 72                   // inpbuf row stride (halves): 144B = 16 mod 128 banks, 16B-aligned
#define WST 72                   // wbuf row stride

typedef _Float16 half8   __attribute__((ext_vector_type(8)));
typedef _Float16 half16  __attribute__((ext_vector_type(16)));
typedef float    floatx4 __attribute__((ext_vector_type(4)));

struct GraphCfg {
    unsigned pred[NN];           // bitmask of predecessors; 0 => source (input = f)
    unsigned sinkmask;
};

// ---------------- fast activations ----------------
__device__ __forceinline__ float act_tanh(float x)     { return 1.0f - 2.0f / (1.0f + __expf(2.0f * x)); }
__device__ __forceinline__ float act_elu(float x)      { return x > 0.0f ? x : __expf(x) - 1.0f; }
__device__ __forceinline__ float act_softplus(float x) { return fmaxf(x, 0.0f) + __logf(1.0f + __expf(-fabsf(x))); }
__device__ __forceinline__ float act_gauss(float x)    { return __expf(-0.5f * x * x); }

__device__ __forceinline__ float apply_act(int a, float x) {
    switch (a) {
        case 0:  return act_tanh(x);
        case 1:  return act_elu(x);
        case 2:  return act_softplus(x);
        case 3:  return __sinf(x);
        default: return act_gauss(x);
    }
}

__device__ __forceinline__ half8 cvt8(float4 a, float4 b) {
    half8 h;
    h[0]=(_Float16)a.x; h[1]=(_Float16)a.y; h[2]=(_Float16)a.z; h[3]=(_Float16)a.w;
    h[4]=(_Float16)b.x; h[5]=(_Float16)b.y; h[6]=(_Float16)b.z; h[7]=(_Float16)b.w;
    return h;
}

// ---------------- main fused kernel ----------------
__global__ __launch_bounds__(256, 4) void inr_mfma_kernel(
    const float* __restrict__ inputs, const float* __restrict__ latents,
    const float* __restrict__ Wl, const float* __restrict__ bl,
    const float* __restrict__ Wx, const float* __restrict__ Wy,
    const float* __restrict__ Wr, const float* __restrict__ W1,
    const float* __restrict__ b1, const float* __restrict__ gW,
    const float* __restrict__ gB, const float* __restrict__ outW,
    const float* __restrict__ outb, const float* __restrict__ scale,
    float* __restrict__ out, int Btot, GraphCfg cfg)
{
    __shared__ __align__(16) _Float16 inpbuf[2][MT * IST];  // [slot][m*IST + k]
    __shared__ __align__(16) _Float16 wbuf[2][W64 * WST];   // [slot][w'*WST + k]

    const int tid  = threadIdx.x;
    const int lane = tid & 63;
    const int wv   = tid >> 6;            // wave id 0..3
    const int q    = lane >> 4;           // quad
    const int c    = lane & 15;           // col-in-tile
    const int rowbase = wv * 16;          // this wave's 16 M-rows within the tile
    const int m0   = blockIdx.x * MT;

    // weight-staging decomposition: thread handles 8-half chunks tid and tid+256
    const int srow = tid >> 3;            // 0..31
    const int sc8  = tid & 7;             // chunk-in-row 0..7

    // h state in MFMA C-layout, PACKED (2 halves/VGPR -> 136 VGPRs worth):
    // hreg[n][t*4+r] = h_n[m = rowbase+q*4+r][w' = t*16+c]; f -> hreg[16].
    half16 hreg[NSTAGE];

    // ---- embed: g0[m][k] -> inpbuf[0]  (thread t: m = t>>2, k-range = (t&3)*16..+15)
    {
        const int em = tid >> 2, ep = tid & 3;
        int mg = m0 + em; if (mg >= Btot) mg = Btot - 1;
        const float x = inputs[mg * 3 + 0];
        const float y = inputs[mg * 3 + 1];
        const float r = inputs[mg * 3 + 2];
        const float4 l0 = *(const float4*)(latents + mg * 8);
        const float4 l1 = *(const float4*)(latents + mg * 8 + 4);
        #pragma unroll
        for (int i = 0; i < 16; ++i) {
            const int k = ep * 16 + i;
            const float4 a = *(const float4*)(Wl + k * 8);
            const float4 b = *(const float4*)(Wl + k * 8 + 4);
            float ld = bl[k];
            ld = fmaf(l0.x, a.x, ld); ld = fmaf(l0.y, a.y, ld);
            ld = fmaf(l0.z, a.z, ld); ld = fmaf(l0.w, a.w, ld);
            ld = fmaf(l1.x, b.x, ld); ld = fmaf(l1.y, b.y, ld);
            ld = fmaf(l1.z, b.z, ld); ld = fmaf(l1.w, b.w, ld);
            const float tk = act_tanh(x * Wx[k]) + act_softplus(y * Wy[k])
                           + act_elu(r * Wr[k]) + act_tanh(ld);
            inpbuf[0][em * IST + k] = (_Float16)act_gauss(tk);
        }
    }
    // ---- stage W1 (fp32 -> fp16) into wbuf[0], padded rows ----
    {
        const float4* src = (const float4*)W1;
        const float4 f0 = src[2 * tid],       f1 = src[2 * tid + 1];
        const float4 f2 = src[2 * tid + 512], f3 = src[2 * tid + 513];
        *(half8*)&wbuf[0][srow * WST + sc8 * 8]        = cvt8(f0, f1);
        *(half8*)&wbuf[0][(srow + 32) * WST + sc8 * 8] = cvt8(f2, f3);
    }
    __syncthreads();

    // ---- stage loop ----
    #pragma unroll
    for (int s = 0; s < NSTAGE; ++s) {
        const int slot = s & 1;

        // prefetch next stage's W (fp32) into regs; stage s+1 uses gW[s]
        float4 nf0, nf1, nf2, nf3;
        if (s + 1 < NSTAGE) {
            const float4* src = (const float4*)(gW + s * 4096);
            nf0 = src[2 * tid];       nf1 = src[2 * tid + 1];
            nf2 = src[2 * tid + 512]; nf3 = src[2 * tid + 513];
        }

        // A fragments: A[m=lane&15][k=quad*8+j], rows rowbase..rowbase+15
        const half8 a0 = *(const half8*)&inpbuf[slot][(rowbase + c) * IST +  0 + q * 8];
        const half8 a1 = *(const half8*)&inpbuf[slot][(rowbase + c) * IST + 32 + q * 8];

        // B fragments from W (stored [w'][k], i.e. B^T rows) + MFMA
        floatx4 acc[4];
        #pragma unroll
        for (int t = 0; t < 4; ++t) {
            const half8 b0  = *(const half8*)&wbuf[slot][(t * 16 + c) * WST +  0 + q * 8];
            const half8 b1f = *(const half8*)&wbuf[slot][(t * 16 + c) * WST + 32 + q * 8];
            floatx4 z = {0.f, 0.f, 0.f, 0.f};
            z = __builtin_amdgcn_mfma_f32_16x16x32_f16(a0, b0, z, 0, 0, 0);
            z = __builtin_amdgcn_mfma_f32_16x16x32_f16(a1, b1f, z, 0, 0, 0);
            acc[t] = z;
        }

        // epilogue: bias + activation -> hreg (C-layout, packed)
        const float* bias = (s == 0) ? b1 : (gB + (s - 1) * W64);
        const int an   = (s == 0) ? 3 : ((s - 1) % 5);   // stage0 act = sin
        const int hidx = (s == 0) ? 16 : (s - 1);
        #pragma unroll
        for (int t = 0; t < 4; ++t) {
            const float bs = bias[t * 16 + c];
            #pragma unroll
            for (int r = 0; r < 4; ++r) {
                const float v = apply_act(an, acc[t][r] + bs);
                hreg[hidx][t * 4 + r] = (_Float16)v;
            }
        }

        // build next stage's input (packed fp16 pred-sum) -> other inp slot;
        // stage next W (convert to fp16) -> other wbuf slot
        if (s + 1 < NSTAGE) {
            const int node = s;                       // stage s+1 computes node s
            const unsigned pm = cfg.pred[node];
            half16 sum;
            if (pm == 0u) {                           // source: input = f
                sum = hreg[16];
            } else {
                #pragma unroll
                for (int v = 0; v < 16; ++v) sum[v] = (_Float16)0.0f;
                #pragma unroll
                for (int i = 0; i < NN; ++i) {
                    if (pm & (1u << i)) {             // wave-uniform branch, i static
                        sum += hreg[i];               // v_pk_add_f16
                    }
                }
            }
            const int wslot = (s + 1) & 1;
            #pragma unroll
            for (int t = 0; t < 4; ++t)
                #pragma unroll
                for (int r = 0; r < 4; ++r)
                    inpbuf[wslot][(rowbase + q * 4 + r) * IST + t * 16 + c] =
                        sum[t * 4 + r];
            *(half8*)&wbuf[wslot][srow * WST + sc8 * 8]        = cvt8(nf0, nf1);
            *(half8*)&wbuf[wslot][(srow + 32) * WST + sc8 * 8] = cvt8(nf2, nf3);
        }
        __syncthreads();
    }

    // ---- head: agg over sinks (packed fp16), LDS round trip, 3 dots, sigmoid ----
    {
        half16 sum;
        #pragma unroll
        for (int v = 0; v < 16; ++v) sum[v] = (_Float16)0.0f;
        #pragma unroll
        for (int j = 0; j < NN; ++j) {
            if (cfg.sinkmask & (1u << j)) {
                sum += hreg[j];
            }
        }
        #pragma unroll
        for (int t = 0; t < 4; ++t)
            #pragma unroll
            for (int r = 0; r < 4; ++r)
                inpbuf[1][(rowbase + q * 4 + r) * IST + t * 16 + c] = sum[t * 4 + r];
    }
    __syncthreads();
    {
        const int em = tid >> 2, ep = tid & 3;
        float p0 = 0.f, p1 = 0.f, p2 = 0.f;
        #pragma unroll
        for (int h = 0; h < 2; ++h) {
            const half8 hv = *(const half8*)&inpbuf[1][em * IST + ep * 16 + h * 8];
            #pragma unroll
            for (int i = 0; i < 8; ++i) {
                const float av = (float)hv[i];
                const int k = ep * 16 + h * 8 + i;
                p0 = fmaf(av, outW[0 * W64 + k], p0);
                p1 = fmaf(av, outW[1 * W64 + k], p1);
                p2 = fmaf(av, outW[2 * W64 + k], p2);
            }
        }
        p0 += __shfl_xor(p0, 1); p0 += __shfl_xor(p0, 2);
        p1 += __shfl_xor(p1, 1); p1 += __shfl_xor(p1, 2);
        p2 += __shfl_xor(p2, 1); p2 += __shfl_xor(p2, 2);
        const int mg = m0 + em;
        if (ep < 3 && mg < Btot) {
            const float pr = (ep == 0) ? p0 : ((ep == 1) ? p1 : p2);
            const float res = (pr + outb[ep]) * scale[0];
            out[mg * 3 + ep] = 1.0f / (1.0f + __expf(-res));
        }
    }
}

// =====================  host side  =====================
// Exact replication of np.random.RandomState(0) draws (validated in R2/R6: passed).
namespace {

struct NpMT {
    unsigned mt[624];
    int mti;
    explicit NpMT(unsigned s) {
        mt[0] = s;
        for (int i = 1; i < 624; ++i)
            mt[i] = 1812433253u * (mt[i-1] ^ (mt[i-1] >> 30)) + (unsigned)i;
        mti = 624;
    }
    unsigned next() {
        if (mti >= 624) {
            for (int i = 0; i < 624; ++i) {
                const unsigned y = (mt[i] & 0x80000000u) | (mt[(i+1) % 624] & 0x7fffffffu);
                unsigned v = mt[(i+397) % 624] ^ (y >> 1);
                if (y & 1u) v ^= 0x9908b0dfu;
                mt[i] = v;
            }
            mti = 0;
        }
        unsigned y = mt[mti++];
        y ^= y >> 11;
        y ^= (y << 7)  & 0x9d2c5680u;
        y ^= (y << 15) & 0xefc60000u;
        y ^= y >> 18;
        return y;
    }
    double rnd() {
        const unsigned a = next() >> 5;
        const unsigned b = next() >> 6;
        return (a * 67108864.0 + b) / 9007199254740992.0;
    }
    long randint(long n) {
        const unsigned long maxv = (unsigned long)n - 1;
        if (maxv == 0) return 0;
        unsigned long mask = maxv;
        mask |= mask >> 1;  mask |= mask >> 2;  mask |= mask >> 4;
        mask |= mask >> 8;  mask |= mask >> 16;
        unsigned long v;
        do { v = (unsigned long)next() & mask; } while (v > maxv);
        return (long)v;
    }
};

static GraphCfg build_graph_cfg() {
    NpMT rng(0u);
    bool edge[NN][NN] = {};
    for (int i = 0; i < NN; ++i) {
        for (int d = 1; d <= 2; ++d) {
            int j = (i + d) & (NN - 1);
            if (rng.rnd() < 0.75) j = (int)rng.randint(NN);
            const int a = i < j ? i : j;
            const int b = i < j ? j : i;
            if (a != b) edge[a][b] = true;
        }
    }
    GraphCfg cfg{};
    for (int a = 0; a < NN; ++a)
        for (int b = 0; b < NN; ++b)
            if (edge[a][b]) cfg.pred[b] |= 1u << a;
    for (int j = 1; j < NN; ++j) {
        if (!cfg.pred[j]) {
            const int a = (int)rng.randint(j);
            cfg.pred[j] |= 1u << a;
            edge[a][j] = true;
        }
    }
    unsigned succ[NN] = {};
    for (int a = 0; a < NN; ++a)
        for (int b = 0; b < NN; ++b)
            if (edge[a][b]) succ[a] |= 1u << b;
    cfg.sinkmask = 0u;
    for (int j = 0; j < NN; ++j)
        if (!succ[j]) cfg.sinkmask |= 1u << j;
    return cfg;
}

} // namespace

extern "C" void kernel_launch(void* const* d_in, const int* in_sizes, int n_in,
                              void* d_out, int out_size, void* d_ws, size_t ws_size,
                              hipStream_t stream)
{
    const float* inputs  = (const float*)d_in[0];
    const float* latents = (const float*)d_in[1];
    const float* Wl      = (const float*)d_in[2];
    const float* bl      = (const float*)d_in[3];
    const float* Wx      = (const float*)d_in[4];
    const float* Wy      = (const float*)d_in[5];
    const float* Wr      = (const float*)d_in[6];
    const float* W1      = (const float*)d_in[7];
    const float* b1      = (const float*)d_in[8];
    const float* gW      = (const float*)d_in[9];
    const float* gB      = (const float*)d_in[10];
    const float* outW    = (const float*)d_in[11];
    const float* outb    = (const float*)d_in[12];
    const float* scale   = (const float*)d_in[13];
    float* out = (float*)d_out;

    const int Btot = in_sizes[0] / 3;
    const GraphCfg cfg = build_graph_cfg();

    const int blocks = (Btot + MT - 1) / MT;
    inr_mfma_kernel<<<blocks, 256, 0, stream>>>(
        inputs, latents, Wl, bl, Wx, Wy, Wr, W1, b1, gW, gB, outW, outb, scale,
        out, Btot, cfg);
}

// Round 8
// 222.026 us; speedup vs baseline: 1.2281x; 1.2281x over previous
//
#include <hip/hip_runtime.h>
#include <cstdint>

#define NN 16
#define W64 64
#define MT 64                    // M elements per workgroup
#define NSTAGE 17                // stage 0 = W1/f, stages 1..16 = graph nodes
#define IST 72                   // inpbuf row stride (halves): 144B = 16 mod 128 banks, 16B-aligned
#define WST 72                   // wbuf row stride

typedef _Float16 half8   __attribute__((ext_vector_type(8)));
typedef _Float16 half16  __attribute__((ext_vector_type(16)));
typedef float    floatx4 __attribute__((ext_vector_type(4)));

struct GraphCfg {
    unsigned pred[NN];           // bitmask of predecessors; 0 => source (input = f)
    unsigned sinkmask;
};

// ---------------- fast activations ----------------
__device__ __forceinline__ float act_tanh(float x)     { return 1.0f - 2.0f / (1.0f + __expf(2.0f * x)); }
__device__ __forceinline__ float act_elu(float x)      { return x > 0.0f ? x : __expf(x) - 1.0f; }
__device__ __forceinline__ float act_softplus(float x) { return fmaxf(x, 0.0f) + __logf(1.0f + __expf(-fabsf(x))); }
__device__ __forceinline__ float act_gauss(float x)    { return __expf(-0.5f * x * x); }

__device__ __forceinline__ float apply_act(int a, float x) {
    switch (a) {
        case 0:  return act_tanh(x);
        case 1:  return act_elu(x);
        case 2:  return act_softplus(x);
        case 3:  return __sinf(x);
        default: return act_gauss(x);
    }
}

__device__ __forceinline__ half8 cvt8(float4 a, float4 b) {
    half8 h;
    h[0]=(_Float16)a.x; h[1]=(_Float16)a.y; h[2]=(_Float16)a.z; h[3]=(_Float16)a.w;
    h[4]=(_Float16)b.x; h[5]=(_Float16)b.y; h[6]=(_Float16)b.z; h[7]=(_Float16)b.w;
    return h;
}

// ---------------- main fused kernel ----------------
// launch_bounds(256, 2): hreg (17 x half16 = 136 regs) must fit the per-wave
// register budget (256 at 2 waves/EU). (256,4) caps at 128 -> full spill of
// hreg to scratch -> 250 MB HBM traffic (measured R7). Do not raise.
__global__ __launch_bounds__(256, 2) void inr_mfma_kernel(
    const float* __restrict__ inputs, const float* __restrict__ latents,
    const float* __restrict__ Wl, const float* __restrict__ bl,
    const float* __restrict__ Wx, const float* __restrict__ Wy,
    const float* __restrict__ Wr, const float* __restrict__ W1,
    const float* __restrict__ b1, const float* __restrict__ gW,
    const float* __restrict__ gB, const float* __restrict__ outW,
    const float* __restrict__ outb, const float* __restrict__ scale,
    float* __restrict__ out, int Btot, GraphCfg cfg)
{
    __shared__ __align__(16) _Float16 inpbuf[2][MT * IST];  // [slot][m*IST + k]
    __shared__ __align__(16) _Float16 wbuf[2][W64 * WST];   // [slot][w'*WST + k]

    const int tid  = threadIdx.x;
    const int lane = tid & 63;
    const int wv   = tid >> 6;            // wave id 0..3
    const int q    = lane >> 4;           // quad
    const int c    = lane & 15;           // col-in-tile
    const int rowbase = wv * 16;          // this wave's 16 M-rows within the tile
    const int m0   = blockIdx.x * MT;

    // weight-staging decomposition: thread handles 8-half chunks tid and tid+256
    const int srow = tid >> 3;            // 0..31
    const int sc8  = tid & 7;             // chunk-in-row 0..7

    // h state in MFMA C-layout, PACKED (2 halves/VGPR -> 136 regs, unified VGPR/AGPR):
    // hreg[n][t*4+r] = h_n[m = rowbase+q*4+r][w' = t*16+c]; f -> hreg[16].
    half16 hreg[NSTAGE];

    // ---- embed: g0[m][k] -> inpbuf[0]  (thread t: m = t>>2, k-range = (t&3)*16..+15)
    {
        const int em = tid >> 2, ep = tid & 3;
        int mg = m0 + em; if (mg >= Btot) mg = Btot - 1;
        const float x = inputs[mg * 3 + 0];
        const float y = inputs[mg * 3 + 1];
        const float r = inputs[mg * 3 + 2];
        const float4 l0 = *(const float4*)(latents + mg * 8);
        const float4 l1 = *(const float4*)(latents + mg * 8 + 4);
        #pragma unroll
        for (int i = 0; i < 16; ++i) {
            const int k = ep * 16 + i;
            const float4 a = *(const float4*)(Wl + k * 8);
            const float4 b = *(const float4*)(Wl + k * 8 + 4);
            float ld = bl[k];
            ld = fmaf(l0.x, a.x, ld); ld = fmaf(l0.y, a.y, ld);
            ld = fmaf(l0.z, a.z, ld); ld = fmaf(l0.w, a.w, ld);
            ld = fmaf(l1.x, b.x, ld); ld = fmaf(l1.y, b.y, ld);
            ld = fmaf(l1.z, b.z, ld); ld = fmaf(l1.w, b.w, ld);
            const float tk = act_tanh(x * Wx[k]) + act_softplus(y * Wy[k])
                           + act_elu(r * Wr[k]) + act_tanh(ld);
            inpbuf[0][em * IST + k] = (_Float16)act_gauss(tk);
        }
    }
    // ---- stage W1 (fp32 -> fp16) into wbuf[0], padded rows ----
    {
        const float4* src = (const float4*)W1;
        const float4 f0 = src[2 * tid],       f1 = src[2 * tid + 1];
        const float4 f2 = src[2 * tid + 512], f3 = src[2 * tid + 513];
        *(half8*)&wbuf[0][srow * WST + sc8 * 8]        = cvt8(f0, f1);
        *(half8*)&wbuf[0][(srow + 32) * WST + sc8 * 8] = cvt8(f2, f3);
    }
    __syncthreads();

    // ---- stage loop ----
    #pragma unroll
    for (int s = 0; s < NSTAGE; ++s) {
        const int slot = s & 1;

        // prefetch next stage's W (fp32) into regs; stage s+1 uses gW[s]
        float4 nf0, nf1, nf2, nf3;
        if (s + 1 < NSTAGE) {
            const float4* src = (const float4*)(gW + s * 4096);
            nf0 = src[2 * tid];       nf1 = src[2 * tid + 1];
            nf2 = src[2 * tid + 512]; nf3 = src[2 * tid + 513];
        }

        // A fragments: A[m=lane&15][k=quad*8+j], rows rowbase..rowbase+15
        const half8 a0 = *(const half8*)&inpbuf[slot][(rowbase + c) * IST +  0 + q * 8];
        const half8 a1 = *(const half8*)&inpbuf[slot][(rowbase + c) * IST + 32 + q * 8];

        // B fragments from W (stored [w'][k], i.e. B^T rows) + MFMA
        floatx4 acc[4];
        #pragma unroll
        for (int t = 0; t < 4; ++t) {
            const half8 b0  = *(const half8*)&wbuf[slot][(t * 16 + c) * WST +  0 + q * 8];
            const half8 b1f = *(const half8*)&wbuf[slot][(t * 16 + c) * WST + 32 + q * 8];
            floatx4 z = {0.f, 0.f, 0.f, 0.f};
            z = __builtin_amdgcn_mfma_f32_16x16x32_f16(a0, b0, z, 0, 0, 0);
            z = __builtin_amdgcn_mfma_f32_16x16x32_f16(a1, b1f, z, 0, 0, 0);
            acc[t] = z;
        }

        // epilogue: bias + activation -> hreg (C-layout, packed)
        const float* bias = (s == 0) ? b1 : (gB + (s - 1) * W64);
        const int an   = (s == 0) ? 3 : ((s - 1) % 5);   // stage0 act = sin
        const int hidx = (s == 0) ? 16 : (s - 1);
        #pragma unroll
        for (int t = 0; t < 4; ++t) {
            const float bs = bias[t * 16 + c];
            #pragma unroll
            for (int r = 0; r < 4; ++r) {
                const float v = apply_act(an, acc[t][r] + bs);
                hreg[hidx][t * 4 + r] = (_Float16)v;
            }
        }

        // build next stage's input (packed fp16 pred-sum) -> other inp slot;
        // stage next W (convert to fp16) -> other wbuf slot
        if (s + 1 < NSTAGE) {
            const int node = s;                       // stage s+1 computes node s
            const unsigned pm = cfg.pred[node];
            half16 sum;
            if (pm == 0u) {                           // source: input = f
                sum = hreg[16];
            } else {
                #pragma unroll
                for (int v = 0; v < 16; ++v) sum[v] = (_Float16)0.0f;
                #pragma unroll
                for (int i = 0; i < NN; ++i) {
                    if (pm & (1u << i)) {             // wave-uniform branch, i static
                        sum += hreg[i];               // v_pk_add_f16
                    }
                }
            }
            const int wslot = (s + 1) & 1;
            #pragma unroll
            for (int t = 0; t < 4; ++t)
                #pragma unroll
                for (int r = 0; r < 4; ++r)
                    inpbuf[wslot][(rowbase + q * 4 + r) * IST + t * 16 + c] =
                        sum[t * 4 + r];
            *(half8*)&wbuf[wslot][srow * WST + sc8 * 8]        = cvt8(nf0, nf1);
            *(half8*)&wbuf[wslot][(srow + 32) * WST + sc8 * 8] = cvt8(nf2, nf3);
        }
        __syncthreads();
    }

    // ---- head: agg over sinks (packed fp16), LDS round trip, 3 dots, sigmoid ----
    {
        half16 sum;
        #pragma unroll
        for (int v = 0; v < 16; ++v) sum[v] = (_Float16)0.0f;
        #pragma unroll
        for (int j = 0; j < NN; ++j) {
            if (cfg.sinkmask & (1u << j)) {
                sum += hreg[j];
            }
        }
        #pragma unroll
        for (int t = 0; t < 4; ++t)
            #pragma unroll
            for (int r = 0; r < 4; ++r)
                inpbuf[1][(rowbase + q * 4 + r) * IST + t * 16 + c] = sum[t * 4 + r];
    }
    __syncthreads();
    {
        const int em = tid >> 2, ep = tid & 3;
        float p0 = 0.f, p1 = 0.f, p2 = 0.f;
        #pragma unroll
        for (int h = 0; h < 2; ++h) {
            const half8 hv = *(const half8*)&inpbuf[1][em * IST + ep * 16 + h * 8];
            #pragma unroll
            for (int i = 0; i < 8; ++i) {
                const float av = (float)hv[i];
                const int k = ep * 16 + h * 8 + i;
                p0 = fmaf(av, outW[0 * W64 + k], p0);
                p1 = fmaf(av, outW[1 * W64 + k], p1);
                p2 = fmaf(av, outW[2 * W64 + k], p2);
            }
        }
        p0 += __shfl_xor(p0, 1); p0 += __shfl_xor(p0, 2);
        p1 += __shfl_xor(p1, 1); p1 += __shfl_xor(p1, 2);
        p2 += __shfl_xor(p2, 1); p2 += __shfl_xor(p2, 2);
        const int mg = m0 + em;
        if (ep < 3 && mg < Btot) {
            const float pr = (ep == 0) ? p0 : ((ep == 1) ? p1 : p2);
            const float res = (pr + outb[ep]) * scale[0];
            out[mg * 3 + ep] = 1.0f / (1.0f + __expf(-res));
        }
    }
}

// =====================  host side  =====================
// Exact replication of np.random.RandomState(0) draws (validated in R2/R6: passed).
namespace {

struct NpMT {
    unsigned mt[624];
    int mti;
    explicit NpMT(unsigned s) {
        mt[0] = s;
        for (int i = 1; i < 624; ++i)
            mt[i] = 1812433253u * (mt[i-1] ^ (mt[i-1] >> 30)) + (unsigned)i;
        mti = 624;
    }
    unsigned next() {
        if (mti >= 624) {
            for (int i = 0; i < 624; ++i) {
                const unsigned y = (mt[i] & 0x80000000u) | (mt[(i+1) % 624] & 0x7fffffffu);
                unsigned v = mt[(i+397) % 624] ^ (y >> 1);
                if (y & 1u) v ^= 0x9908b0dfu;
                mt[i] = v;
            }
            mti = 0;
        }
        unsigned y = mt[mti++];
        y ^= y >> 11;
        y ^= (y << 7)  & 0x9d2c5680u;
        y ^= (y << 15) & 0xefc60000u;
        y ^= y >> 18;
        return y;
    }
    double rnd() {
        const unsigned a = next() >> 5;
        const unsigned b = next() >> 6;
        return (a * 67108864.0 + b) / 9007199254740992.0;
    }
    long randint(long n) {
        const unsigned long maxv = (unsigned long)n - 1;
        if (maxv == 0) return 0;
        unsigned long mask = maxv;
        mask |= mask >> 1;  mask |= mask >> 2;  mask |= mask >> 4;
        mask |= mask >> 8;  mask |= mask >> 16;
        unsigned long v;
        do { v = (unsigned long)next() & mask; } while (v > maxv);
        return (long)v;
    }
};

static GraphCfg build_graph_cfg() {
    NpMT rng(0u);
    bool edge[NN][NN] = {};
    for (int i = 0; i < NN; ++i) {
        for (int d = 1; d <= 2; ++d) {
            int j = (i + d) & (NN - 1);
            if (rng.rnd() < 0.75) j = (int)rng.randint(NN);
            const int a = i < j ? i : j;
            const int b = i < j ? j : i;
            if (a != b) edge[a][b] = true;
        }
    }
    GraphCfg cfg{};
    for (int a = 0; a < NN; ++a)
        for (int b = 0; b < NN; ++b)
            if (edge[a][b]) cfg.pred[b] |= 1u << a;
    for (int j = 1; j < NN; ++j) {
        if (!cfg.pred[j]) {
            const int a = (int)rng.randint(j);
            cfg.pred[j] |= 1u << a;
            edge[a][j] = true;
        }
    }
    unsigned succ[NN] = {};
    for (int a = 0; a < NN; ++a)
        for (int b = 0; b < NN; ++b)
            if (edge[a][b]) succ[a] |= 1u << b;
    cfg.sinkmask = 0u;
    for (int j = 0; j < NN; ++j)
        if (!succ[j]) cfg.sinkmask |= 1u << j;
    return cfg;
}

} // namespace

extern "C" void kernel_launch(void* const* d_in, const int* in_sizes, int n_in,
                              void* d_out, int out_size, void* d_ws, size_t ws_size,
                              hipStream_t stream)
{
    const float* inputs  = (const float*)d_in[0];
    const float* latents = (const float*)d_in[1];
    const float* Wl      = (const float*)d_in[2];
    const float* bl      = (const float*)d_in[3];
    const float* Wx      = (const float*)d_in[4];
    const float* Wy      = (const float*)d_in[5];
    const float* Wr      = (const float*)d_in[6];
    const float* W1      = (const float*)d_in[7];
    const float* b1      = (const float*)d_in[8];
    const float* gW      = (const float*)d_in[9];
    const float* gB      = (const float*)d_in[10];
    const float* outW    = (const float*)d_in[11];
    const float* outb    = (const float*)d_in[12];
    const float* scale   = (const float*)d_in[13];
    float* out = (float*)d_out;

    const int Btot = in_sizes[0] / 3;
    const GraphCfg cfg = build_graph_cfg();

    const int blocks = (Btot + MT - 1) / MT;
    inr_mfma_kernel<<<blocks, 256, 0, stream>>>(
        inputs, latents, Wl, bl, Wx, Wy, Wr, W1, b1, gW, gB, outW, outb, scale,
        out, Btot, cfg);
}

// Round 9
// 194.426 us; speedup vs baseline: 1.4024x; 1.1420x over previous
//
#include <hip/hip_runtime.h>
#include <cstdint>

#define NN 16
#define W64 64
#define MT 64                    // M elements per workgroup
#define NSTAGE 17                // stage 0 = W1/f, stages 1..16 = graph nodes
#define IST 72                   // inpbuf row stride (halves): 144B = 16 mod 128 banks
#define WST 72                   // wbuf row stride

typedef _Float16 half8   __attribute__((ext_vector_type(8)));
typedef _Float16 half16  __attribute__((ext_vector_type(16)));
typedef float    floatx4 __attribute__((ext_vector_type(4)));

// ================== compile-time graph (np.random.RandomState(0)) ==================
// Same MT19937 + build_graph algorithm validated on-device in R2/R6/R8, evaluated
// at compile time so pred masks fold to constants and node tiles get live-range-
// compressed register slots.
struct GPlan {
    unsigned pred[NN];
    unsigned sinkmask;
    int slot[NSTAGE];            // slot[i]: node i (i<16); slot[16] = f
    int nslot;
};

constexpr unsigned mt_next(unsigned (&mt)[624], int &mti) {
    if (mti >= 624) {
        for (int i = 0; i < 624; ++i) {
            const unsigned y = (mt[i] & 0x80000000u) | (mt[(i + 1) % 624] & 0x7fffffffu);
            unsigned v = mt[(i + 397) % 624] ^ (y >> 1);
            if (y & 1u) v ^= 0x9908b0dfu;
            mt[i] = v;
        }
        mti = 0;
    }
    unsigned y = mt[mti++];
    y ^= y >> 11;
    y ^= (y << 7)  & 0x9d2c5680u;
    y ^= (y << 15) & 0xefc60000u;
    y ^= y >> 18;
    return y;
}
constexpr double mt_rnd(unsigned (&mt)[624], int &mti) {
    const unsigned a = mt_next(mt, mti) >> 5;    // 27 bits
    const unsigned b = mt_next(mt, mti) >> 6;    // 26 bits
    return (a * 67108864.0 + b) / 9007199254740992.0;
}
constexpr long mt_randint(unsigned (&mt)[624], int &mti, long n) {
    const unsigned long maxv = (unsigned long)n - 1;
    if (maxv == 0) return 0;                     // no draw consumed
    unsigned long mask = maxv;
    mask |= mask >> 1;  mask |= mask >> 2;  mask |= mask >> 4;
    mask |= mask >> 8;  mask |= mask >> 16;
    unsigned long v = (unsigned long)mt_next(mt, mti) & mask;
    while (v > maxv) v = (unsigned long)mt_next(mt, mti) & mask;
    return (long)v;
}

constexpr GPlan build_plan() {
    GPlan P = {};
    unsigned mt[624] = {};
    mt[0] = 0u;
    for (int i = 1; i < 624; ++i)
        mt[i] = 1812433253u * (mt[i-1] ^ (mt[i-1] >> 30)) + (unsigned)i;
    int mti = 624;

    bool edge[NN][NN] = {};
    for (int i = 0; i < NN; ++i) {
        for (int d = 1; d <= 2; ++d) {           // k=4 -> d in {1,2}
            int j = (i + d) & (NN - 1);
            if (mt_rnd(mt, mti) < 0.75) j = (int)mt_randint(mt, mti, NN);
            const int a = i < j ? i : j;
            const int b = i < j ? j : i;
            if (a != b) edge[a][b] = true;
        }
    }
    for (int a = 0; a < NN; ++a)
        for (int b = 0; b < NN; ++b)
            if (edge[a][b]) P.pred[b] |= 1u << a;
    for (int j = 1; j < NN; ++j) {
        if (!P.pred[j]) {
            const int a = (int)mt_randint(mt, mti, j);
            P.pred[j] |= 1u << a;
            edge[a][j] = true;
        }
    }
    unsigned succ[NN] = {};
    for (int a = 0; a < NN; ++a)
        for (int b = 0; b < NN; ++b)
            if (edge[a][b]) succ[a] |= 1u << b;
    for (int j = 0; j < NN; ++j)
        if (!succ[j]) P.sinkmask |= 1u << j;

    // ---- live ranges: value i (node) defined at stage i+1; f (=16) at stage 0.
    // Reads: node j's input built during stage j (reads preds / f if source).
    // Sinks read at head ("stage 17").
    int lastuse[NSTAGE] = {};
    for (int v = 0; v < NSTAGE; ++v) lastuse[v] = -1;
    for (int j = 0; j < NN; ++j) {
        const unsigned pm = P.pred[j];
        if (pm == 0u) { if (j > lastuse[16]) lastuse[16] = j; }
        else for (int i = 0; i < NN; ++i)
            if (pm & (1u << i)) { if (j > lastuse[i]) lastuse[i] = j; }
    }
    for (int i = 0; i < NN; ++i)
        if (P.sinkmask & (1u << i)) lastuse[i] = 17;

    int defstage[NSTAGE] = {};
    for (int i = 0; i < NN; ++i) defstage[i] = i + 1;
    defstage[16] = 0;

    // greedy interval slot allocation (def happens before same-stage reads,
    // so a value with lastuse==s still blocks its slot for a def at stage s)
    int nmax = 0;
    for (int s = 0; s <= 16; ++s) {
        const int w = (s == 0) ? 16 : (s - 1);
        bool busy[NSTAGE] = {};
        for (int v = 0; v < NSTAGE; ++v) {
            if (v == w) continue;
            if (defstage[v] < s && lastuse[v] >= s)
                busy[P.slot[v]] = true;
        }
        int k = 0;
        while (busy[k]) ++k;
        P.slot[w] = k;
        if (k + 1 > nmax) nmax = k + 1;
    }
    P.nslot = nmax;
    return P;
}

constexpr GPlan kPlan = build_plan();
constexpr int NSLOT = kPlan.nslot;

// ---------------- fast activations ----------------
__device__ __forceinline__ float act_tanh(float x)     { return 1.0f - 2.0f / (1.0f + __expf(2.0f * x)); }
__device__ __forceinline__ float act_elu(float x)      { return x > 0.0f ? x : __expf(x) - 1.0f; }
__device__ __forceinline__ float act_softplus(float x) { return fmaxf(x, 0.0f) + __logf(1.0f + __expf(-fabsf(x))); }
__device__ __forceinline__ float act_gauss(float x)    { return __expf(-0.5f * x * x); }

__device__ __forceinline__ float apply_act(int a, float x) {
    switch (a) {
        case 0:  return act_tanh(x);
        case 1:  return act_elu(x);
        case 2:  return act_softplus(x);
        case 3:  return __sinf(x);
        default: return act_gauss(x);
    }
}

__device__ __forceinline__ half8 cvt8(float4 a, float4 b) {
    half8 h;
    h[0]=(_Float16)a.x; h[1]=(_Float16)a.y; h[2]=(_Float16)a.z; h[3]=(_Float16)a.w;
    h[4]=(_Float16)b.x; h[5]=(_Float16)b.y; h[6]=(_Float16)b.z; h[7]=(_Float16)b.w;
    return h;
}

// ---------------- main fused kernel ----------------
// (256,3): NSLOT-compressed hreg frees ~(17-NSLOT)*8 regs vs R8; targeting
// 3 waves/EU. If WRITE_SIZE blows up -> spill -> revert to (256,2).
__global__ __launch_bounds__(256, 3) void inr_mfma_kernel(
    const float* __restrict__ inputs, const float* __restrict__ latents,
    const float* __restrict__ Wl, const float* __restrict__ bl,
    const float* __restrict__ Wx, const float* __restrict__ Wy,
    const float* __restrict__ Wr, const float* __restrict__ W1,
    const float* __restrict__ b1, const float* __restrict__ gW,
    const float* __restrict__ gB, const float* __restrict__ outW,
    const float* __restrict__ outb, const float* __restrict__ scale,
    float* __restrict__ out, int Btot)
{
    __shared__ __align__(16) _Float16 inpbuf[2][MT * IST];  // [slot][m*IST + k]
    __shared__ __align__(16) _Float16 wbuf[2][W64 * WST];   // [slot][w'*WST + k]

    const int tid  = threadIdx.x;
    const int lane = tid & 63;
    const int wv   = tid >> 6;            // wave id 0..3
    const int q    = lane >> 4;           // quad
    const int c    = lane & 15;           // col-in-tile
    const int rowbase = wv * 16;          // this wave's 16 M-rows within the tile
    const int m0   = blockIdx.x * MT;

    // weight-staging decomposition: thread handles 8-half chunks tid and tid+256
    const int srow = tid >> 3;            // 0..31
    const int sc8  = tid & 7;             // chunk-in-row 0..7

    // node state in MFMA C-layout, slot-compressed:
    // hreg[kPlan.slot[n]][t*4+r] = h_n[m = rowbase+q*4+r][w' = t*16+c]
    half16 hreg[NSLOT];

    // ---- embed: g0[m][k] -> inpbuf[0]  (thread t: m = t>>2, k-range = (t&3)*16..+15)
    {
        const int em = tid >> 2, ep = tid & 3;
        int mg = m0 + em; if (mg >= Btot) mg = Btot - 1;
        const float x = inputs[mg * 3 + 0];
        const float y = inputs[mg * 3 + 1];
        const float r = inputs[mg * 3 + 2];
        const float4 l0 = *(const float4*)(latents + mg * 8);
        const float4 l1 = *(const float4*)(latents + mg * 8 + 4);
        #pragma unroll
        for (int i = 0; i < 16; ++i) {
            const int k = ep * 16 + i;
            const float4 a = *(const float4*)(Wl + k * 8);
            const float4 b = *(const float4*)(Wl + k * 8 + 4);
            float ld = bl[k];
            ld = fmaf(l0.x, a.x, ld); ld = fmaf(l0.y, a.y, ld);
            ld = fmaf(l0.z, a.z, ld); ld = fmaf(l0.w, a.w, ld);
            ld = fmaf(l1.x, b.x, ld); ld = fmaf(l1.y, b.y, ld);
            ld = fmaf(l1.z, b.z, ld); ld = fmaf(l1.w, b.w, ld);
            const float tk = act_tanh(x * Wx[k]) + act_softplus(y * Wy[k])
                           + act_elu(r * Wr[k]) + act_tanh(ld);
            inpbuf[0][em * IST + k] = (_Float16)act_gauss(tk);
        }
    }
    // ---- stage W1 (fp32 -> fp16) into wbuf[0], padded rows ----
    {
        const float4* src = (const float4*)W1;
        const float4 f0 = src[2 * tid],       f1 = src[2 * tid + 1];
        const float4 f2 = src[2 * tid + 512], f3 = src[2 * tid + 513];
        *(half8*)&wbuf[0][srow * WST + sc8 * 8]        = cvt8(f0, f1);
        *(half8*)&wbuf[0][(srow + 32) * WST + sc8 * 8] = cvt8(f2, f3);
    }
    __syncthreads();

    // ---- stage loop ----
    #pragma unroll
    for (int s = 0; s < NSTAGE; ++s) {
        const int slot = s & 1;

        // prefetch next stage's W (fp32) into regs; stage s+1 uses gW[s]
        float4 nf0, nf1, nf2, nf3;
        if (s + 1 < NSTAGE) {
            const float4* src = (const float4*)(gW + s * 4096);
            nf0 = src[2 * tid];       nf1 = src[2 * tid + 1];
            nf2 = src[2 * tid + 512]; nf3 = src[2 * tid + 513];
        }

        // A fragments: A[m=lane&15][k=quad*8+j], rows rowbase..rowbase+15
        const half8 a0 = *(const half8*)&inpbuf[slot][(rowbase + c) * IST +  0 + q * 8];
        const half8 a1 = *(const half8*)&inpbuf[slot][(rowbase + c) * IST + 32 + q * 8];

        // B fragments from W (stored [w'][k], i.e. B^T rows) + MFMA
        floatx4 acc[4];
        #pragma unroll
        for (int t = 0; t < 4; ++t) {
            const half8 b0  = *(const half8*)&wbuf[slot][(t * 16 + c) * WST +  0 + q * 8];
            const half8 b1f = *(const half8*)&wbuf[slot][(t * 16 + c) * WST + 32 + q * 8];
            floatx4 z = {0.f, 0.f, 0.f, 0.f};
            z = __builtin_amdgcn_mfma_f32_16x16x32_f16(a0, b0, z, 0, 0, 0);
            z = __builtin_amdgcn_mfma_f32_16x16x32_f16(a1, b1f, z, 0, 0, 0);
            acc[t] = z;
        }

        // epilogue: bias + activation -> hreg slot (C-layout, packed)
        const float* bias = (s == 0) ? b1 : (gB + (s - 1) * W64);
        const int an    = (s == 0) ? 3 : ((s - 1) % 5);     // stage0 act = sin
        const int hslot = kPlan.slot[(s == 0) ? 16 : (s - 1)];  // folds per-iteration
        #pragma unroll
        for (int t = 0; t < 4; ++t) {
            const float bs = bias[t * 16 + c];
            #pragma unroll
            for (int r = 0; r < 4; ++r) {
                const float v = apply_act(an, acc[t][r] + bs);
                hreg[hslot][t * 4 + r] = (_Float16)v;
            }
        }

        // build next stage's input (packed fp16 pred-sum, masks fold statically)
        if (s + 1 < NSTAGE) {
            const unsigned pm = kPlan.pred[s];    // compile-time constant
            half16 sum;
            if (pm == 0u) {                       // source: input = f
                sum = hreg[kPlan.slot[16]];
            } else {
                #pragma unroll
                for (int v = 0; v < 16; ++v) sum[v] = (_Float16)0.0f;
                #pragma unroll
                for (int i = 0; i < NN; ++i) {
                    if (pm & (1u << i)) {         // folds: dead branches removed
                        sum += hreg[kPlan.slot[i]];
                    }
                }
            }
            const int wslot = (s + 1) & 1;
            #pragma unroll
            for (int t = 0; t < 4; ++t)
                #pragma unroll
                for (int r = 0; r < 4; ++r)
                    inpbuf[wslot][(rowbase + q * 4 + r) * IST + t * 16 + c] =
                        sum[t * 4 + r];
            *(half8*)&wbuf[wslot][srow * WST + sc8 * 8]        = cvt8(nf0, nf1);
            *(half8*)&wbuf[wslot][(srow + 32) * WST + sc8 * 8] = cvt8(nf2, nf3);
        }
        __syncthreads();
    }

    // ---- head: agg over sinks (packed fp16), LDS round trip, 3 dots, sigmoid ----
    {
        half16 sum;
        #pragma unroll
        for (int v = 0; v < 16; ++v) sum[v] = (_Float16)0.0f;
        #pragma unroll
        for (int j = 0; j < NN; ++j) {
            if (kPlan.sinkmask & (1u << j)) {     // folds statically
                sum += hreg[kPlan.slot[j]];
            }
        }
        #pragma unroll
        for (int t = 0; t < 4; ++t)
            #pragma unroll
            for (int r = 0; r < 4; ++r)
                inpbuf[1][(rowbase + q * 4 + r) * IST + t * 16 + c] = sum[t * 4 + r];
    }
    __syncthreads();
    {
        const int em = tid >> 2, ep = tid & 3;
        float p0 = 0.f, p1 = 0.f, p2 = 0.f;
        #pragma unroll
        for (int h = 0; h < 2; ++h) {
            const half8 hv = *(const half8*)&inpbuf[1][em * IST + ep * 16 + h * 8];
            #pragma unroll
            for (int i = 0; i < 8; ++i) {
                const float av = (float)hv[i];
                const int k = ep * 16 + h * 8 + i;
                p0 = fmaf(av, outW[0 * W64 + k], p0);
                p1 = fmaf(av, outW[1 * W64 + k], p1);
                p2 = fmaf(av, outW[2 * W64 + k], p2);
            }
        }
        p0 += __shfl_xor(p0, 1); p0 += __shfl_xor(p0, 2);
        p1 += __shfl_xor(p1, 1); p1 += __shfl_xor(p1, 2);
        p2 += __shfl_xor(p2, 1); p2 += __shfl_xor(p2, 2);
        const int mg = m0 + em;
        if (ep < 3 && mg < Btot) {
            const float pr = (ep == 0) ? p0 : ((ep == 1) ? p1 : p2);
            const float res = (pr + outb[ep]) * scale[0];
            out[mg * 3 + ep] = 1.0f / (1.0f + __expf(-res));
        }
    }
}

extern "C" void kernel_launch(void* const* d_in, const int* in_sizes, int n_in,
                              void* d_out, int out_size, void* d_ws, size_t ws_size,
                              hipStream_t stream)
{
    const float* inputs  = (const float*)d_in[0];
    const float* latents = (const float*)d_in[1];
    const float* Wl      = (const float*)d_in[2];
    const float* bl      = (const float*)d_in[3];
    const float* Wx      = (const float*)d_in[4];
    const float* Wy      = (const float*)d_in[5];
    const float* Wr      = (const float*)d_in[6];
    const float* W1      = (const float*)d_in[7];
    const float* b1      = (const float*)d_in[8];
    const float* gW      = (const float*)d_in[9];
    const float* gB      = (const float*)d_in[10];
    const float* outW    = (const float*)d_in[11];
    const float* outb    = (const float*)d_in[12];
    const float* scale   = (const float*)d_in[13];
    float* out = (float*)d_out;

    const int Btot = in_sizes[0] / 3;
    const int blocks = (Btot + MT - 1) / MT;
    inr_mfma_kernel<<<blocks, 256, 0, stream>>>(
        inputs, latents, Wl, bl, Wx, Wy, Wr, W1, b1, gW, gB, outW, outb, scale,
        out, Btot);
}